// Round 4
// baseline (55.280 us; speedup 1.0000x reference)
//
#include <hip/hip_runtime.h>

// Chamfer loss: pred (8,4096,3) f32, target (8,4096,3) f32 -> scalar f32.
// dist = |q|^2 + (|t|^2 - 2 q.t). Inner loop: min_t over a 3-FMA chain seeded
// from precomputed |t|^2; |q|^2 added once after the loop. 2 targets/iter ->
// fminf(fminf(d0,d1),mn) fuses to v_min3_f32 => 3.5 VALU/pair.
//
// Round-4 structure: a pack pass builds SoA float4(x,y,z,|p|^2) for both
// clouds (1 MB, L2-resident) so the min kernel's per-block setup is 8
// coalesced dwordx4 loads instead of 24 strided scalar loads (round-3
// post-mortem: setup latency, not occupancy, was the limiter).

#define BATCH 8
#define NPTS  4096
#define TPB   256
#define Q     8                     // queries per thread
#define QTILE (TPB * Q)             // 2048 queries per block
#define NQT   (NPTS / QTILE)        // 2
#define NQ_TOTAL (2 * BATCH * NPTS) // 65536 query slots (both directions)
#define NPTS_ALL (2 * BATCH * NPTS) // 65536 points to pack

// ---- primary path ----
#define NCH2   64
#define CHUNK2 (NPTS / NCH2)        // 64 targets staged per block

// pack: (x,y,z) strided -> float4(x,y,z,x^2+y^2+z^2). pp4 then tt4.
__global__ __launch_bounds__(TPB)
void chamfer_pack(const float* __restrict__ pred,
                  const float* __restrict__ tgt,
                  float4* __restrict__ packed /* [2][BATCH*NPTS] */)
{
    int idx = blockIdx.x * TPB + threadIdx.x;     // 0..65535
    const float* src = (idx < BATCH * NPTS) ? pred : tgt;
    int p = (idx < BATCH * NPTS) ? idx : idx - BATCH * NPTS;
    float x = src[3 * p + 0];
    float y = src[3 * p + 1];
    float z = src[3 * p + 2];
    packed[idx] = make_float4(x, y, z, x * x + y * y + z * z);
}

__global__ __launch_bounds__(TPB, 8)   // 8 waves/SIMD, VGPR cap 64 (uses ~56)
void chamfer_min_slots(const float4* __restrict__ pp4,
                       const float4* __restrict__ tt4,
                       float* __restrict__ part /* [NCH2][NQ_TOTAL] */)
{
    int bid = blockIdx.x;
    const int per_dir = BATCH * NQT * NCH2;       // 1024
    int dir = bid / per_dir;
    int r   = bid - dir * per_dir;
    int b   = r / (NQT * NCH2);
    r      -= b * (NQT * NCH2);
    int qt  = r / NCH2;
    int ch  = r - qt * NCH2;

    const float4* qsrc = dir ? tt4 : pp4;
    const float4* csrc = dir ? pp4 : tt4;

    __shared__ float4 sc[CHUNK2];

    // Issue the staging load first so it overlaps the query loads.
    float4 stage;
    if (threadIdx.x < CHUNK2)
        stage = csrc[b * NPTS + ch * CHUNK2 + threadIdx.x];

    // 8 coalesced dwordx4 query loads (lane-contiguous at stride TPB).
    const int q0 = qt * QTILE + threadIdx.x;
    float4 q4[Q];
#pragma unroll
    for (int i = 0; i < Q; ++i)
        q4[i] = qsrc[b * NPTS + q0 + i * TPB];

    if (threadIdx.x < CHUNK2)
        sc[threadIdx.x] = stage;

    float ax[Q], ay[Q], az[Q], w[Q], mn[Q];
#pragma unroll
    for (int i = 0; i < Q; ++i) {
        ax[i] = -2.0f * q4[i].x;
        ay[i] = -2.0f * q4[i].y;
        az[i] = -2.0f * q4[i].z;
        w[i]  = q4[i].w;
        mn[i] = 3.0e38f;
    }
    __syncthreads();

#pragma unroll 4
    for (int j = 0; j < CHUNK2; j += 2) {
        float4 t0 = sc[j];        // uniform addr -> ds_read_b128 broadcast
        float4 t1 = sc[j + 1];
#pragma unroll
        for (int i = 0; i < Q; ++i) {
            float d0 = fmaf(az[i], t0.z, fmaf(ay[i], t0.y, fmaf(ax[i], t0.x, t0.w)));
            float d1 = fmaf(az[i], t1.z, fmaf(ay[i], t1.y, fmaf(ax[i], t1.x, t1.w)));
            mn[i] = fminf(fminf(d0, d1), mn[i]);   // v_min3_f32
        }
    }

    float* pslot = part + (size_t)ch * NQ_TOTAL
                 + (size_t)dir * (BATCH * NPTS) + (size_t)b * NPTS;
#pragma unroll
    for (int i = 0; i < Q; ++i)
        pslot[q0 + i * TPB] = w[i] + mn[i];        // coalesced stores
}

// per-query min across NCH2 chunks, block-sum, one atomicAdd per block.
__global__ __launch_bounds__(TPB)
void chamfer_reduce_slots(const float* __restrict__ part,
                          float* __restrict__ out)
{
    int q = blockIdx.x * TPB + threadIdx.x;        // one query per thread
    float m = part[q];
#pragma unroll 16
    for (int c = 1; c < NCH2; ++c)
        m = fminf(m, part[(size_t)c * NQ_TOTAL + q]);

#pragma unroll
    for (int o = 32; o; o >>= 1) m += __shfl_down(m, o);
    __shared__ float acc[TPB / 64];
    int lane = threadIdx.x & 63, wid = threadIdx.x >> 6;
    if (lane == 0) acc[wid] = m;
    __syncthreads();
    if (threadIdx.x == 0) {
        float s = 0.0f;
#pragma unroll
        for (int i = 0; i < TPB / 64; ++i) s += acc[i];
        atomicAdd(out, s * (1.0f / (BATCH * NPTS)));
    }
}

// ---- secondary path (>=256 KB ws): atomicMin on uint-encoded nonneg floats ----
#define CHUNK 512
#define NCH   (NPTS / CHUNK)

__global__ __launch_bounds__(TPB)
void chamfer_partial_min(const float* __restrict__ pred,
                         const float* __restrict__ tgt,
                         unsigned int* __restrict__ mins)
{
    int bid = blockIdx.x;
    const int per_dir = BATCH * NQT * NCH;
    int dir = bid / per_dir;
    int r   = bid - dir * per_dir;
    int b   = r / (NQT * NCH);
    r      -= b * (NQT * NCH);
    int qt  = r / NCH;
    int ch  = r - qt * NCH;

    const float* qsrc = dir ? tgt  : pred;
    const float* csrc = dir ? pred : tgt;
    unsigned int* mout = mins + (size_t)dir * (BATCH * NPTS) + (size_t)b * NPTS;

    __shared__ float4 sc[CHUNK];
    {
        const float* cbase = csrc + (size_t)(b * NPTS + ch * CHUNK) * 3;
        for (int p = threadIdx.x; p < CHUNK; p += TPB) {
            float x = cbase[3 * p + 0];
            float y = cbase[3 * p + 1];
            float z = cbase[3 * p + 2];
            sc[p] = make_float4(x, y, z, x * x + y * y + z * z);
        }
    }
    __syncthreads();

    float ax[Q], ay[Q], az[Q], w[Q], mn[Q];
    const int q0 = qt * QTILE + threadIdx.x;
#pragma unroll
    for (int i = 0; i < Q; ++i) {
        int q = q0 + i * TPB;
        const float* qp = qsrc + (size_t)(b * NPTS + q) * 3;
        float x = qp[0], y = qp[1], z = qp[2];
        ax[i] = -2.0f * x; ay[i] = -2.0f * y; az[i] = -2.0f * z;
        w[i]  = x * x + y * y + z * z;
        mn[i] = 3.0e38f;
    }
#pragma unroll 4
    for (int j = 0; j < CHUNK; j += 2) {
        float4 t0 = sc[j], t1 = sc[j + 1];
#pragma unroll
        for (int i = 0; i < Q; ++i) {
            float d0 = fmaf(az[i], t0.z, fmaf(ay[i], t0.y, fmaf(ax[i], t0.x, t0.w)));
            float d1 = fmaf(az[i], t1.z, fmaf(ay[i], t1.y, fmaf(ax[i], t1.x, t1.w)));
            mn[i] = fminf(fminf(d0, d1), mn[i]);
        }
    }
#pragma unroll
    for (int i = 0; i < Q; ++i)
        atomicMin(&mout[q0 + i * TPB], __float_as_uint(fmaxf(w[i] + mn[i], 0.0f)));
}

__global__ __launch_bounds__(1024)
void chamfer_reduce(const unsigned int* __restrict__ mins,
                    float* __restrict__ out)
{
    float s0 = 0.0f, s1 = 0.0f;
    for (int i = threadIdx.x; i < BATCH * NPTS; i += 1024) {
        s0 += __uint_as_float(mins[i]);
        s1 += __uint_as_float(mins[BATCH * NPTS + i]);
    }
#pragma unroll
    for (int o = 32; o; o >>= 1) { s0 += __shfl_down(s0, o); s1 += __shfl_down(s1, o); }
    __shared__ float a0[16], a1[16];
    int lane = threadIdx.x & 63, wid = threadIdx.x >> 6;
    if (lane == 0) { a0[wid] = s0; a1[wid] = s1; }
    __syncthreads();
    if (threadIdx.x == 0) {
        float t0 = 0.0f, t1 = 0.0f;
#pragma unroll
        for (int i = 0; i < 16; ++i) { t0 += a0[i]; t1 += a1[i]; }
        out[0] = (t0 + t1) * (1.0f / (BATCH * NPTS));
    }
}

// ---- tertiary path (no usable ws) ----
__global__ __launch_bounds__(TPB)
void chamfer_fallback(const float* __restrict__ pred,
                      const float* __restrict__ tgt,
                      float* __restrict__ out)
{
    int bid = blockIdx.x;
    const int per_dir = BATCH * (NPTS / TPB);
    int dir = bid / per_dir;
    int r   = bid - dir * per_dir;
    int b   = r / (NPTS / TPB);
    int qt  = r % (NPTS / TPB);

    const float* qsrc = dir ? tgt  : pred;
    const float* csrc = dir ? pred : tgt;

    __shared__ float4 sc[CHUNK];
    int q = qt * TPB + threadIdx.x;
    const float* qp = qsrc + (size_t)(b * NPTS + q) * 3;
    float x = qp[0], y = qp[1], z = qp[2];
    float ax = -2.0f * x, ay = -2.0f * y, az = -2.0f * z;
    float w = x * x + y * y + z * z;
    float mn = 3.0e38f;

    for (int ch = 0; ch < NCH; ++ch) {
        __syncthreads();
        const float* cbase = csrc + (size_t)(b * NPTS + ch * CHUNK) * 3;
        for (int p = threadIdx.x; p < CHUNK; p += TPB) {
            float tx = cbase[3 * p + 0];
            float ty = cbase[3 * p + 1];
            float tz = cbase[3 * p + 2];
            sc[p] = make_float4(tx, ty, tz, tx * tx + ty * ty + tz * tz);
        }
        __syncthreads();
#pragma unroll 4
        for (int j = 0; j < CHUNK; ++j) {
            float4 t = sc[j];
            float d = fmaf(az, t.z, fmaf(ay, t.y, fmaf(ax, t.x, t.w)));
            mn = fminf(mn, d);
        }
    }
    mn += w;
#pragma unroll
    for (int o = 32; o; o >>= 1) mn += __shfl_down(mn, o);
    __shared__ float acc[TPB / 64];
    int lane = threadIdx.x & 63, wid = threadIdx.x >> 6;
    if (lane == 0) acc[wid] = mn;
    __syncthreads();
    if (threadIdx.x == 0) {
        float s = 0.0f;
#pragma unroll
        for (int i = 0; i < TPB / 64; ++i) s += acc[i];
        atomicAdd(out, s * (1.0f / (BATCH * NPTS)));
    }
}

extern "C" void kernel_launch(void* const* d_in, const int* in_sizes, int n_in,
                              void* d_out, int out_size, void* d_ws, size_t ws_size,
                              hipStream_t stream)
{
    const float* pred = (const float*)d_in[0];
    const float* tgt  = (const float*)d_in[1];
    float* out = (float*)d_out;

    const size_t pack_bytes = (size_t)NPTS_ALL * sizeof(float4);         // 1 MB
    const size_t part_bytes = (size_t)NCH2 * NQ_TOTAL * sizeof(float);   // 16 MB
    const size_t need_slots = pack_bytes + part_bytes;
    const size_t need_amin  = (size_t)NQ_TOTAL * sizeof(unsigned int);   // 256 KB

    if (ws_size >= need_slots) {
        float4* packed = (float4*)d_ws;                 // pp4 then tt4
        float*  part   = (float*)((char*)d_ws + pack_bytes);
        hipMemsetAsync(d_out, 0, sizeof(float), stream);
        chamfer_pack<<<NPTS_ALL / TPB, TPB, 0, stream>>>(pred, tgt, packed);
        chamfer_min_slots<<<2 * BATCH * NQT * NCH2, TPB, 0, stream>>>(
            packed, packed + BATCH * NPTS, part);
        chamfer_reduce_slots<<<NQ_TOTAL / TPB, TPB, 0, stream>>>(part, out);
    } else if (ws_size >= need_amin) {
        unsigned int* mins = (unsigned int*)d_ws;
        hipMemsetAsync(d_ws, 0x7F, need_amin, stream);
        chamfer_partial_min<<<2 * BATCH * NQT * NCH, TPB, 0, stream>>>(pred, tgt, mins);
        chamfer_reduce<<<1, 1024, 0, stream>>>(mins, out);
    } else {
        hipMemsetAsync(d_out, 0, sizeof(float), stream);
        chamfer_fallback<<<2 * BATCH * (NPTS / TPB), TPB, 0, stream>>>(pred, tgt, out);
    }
}